// Round 17
// baseline (484.240 us; speedup 1.0000x reference)
//
#include <hip/hip_runtime.h>

#define EPS_ 1e-5f

typedef __attribute__((ext_vector_type(8))) short bf16x8;
typedef __attribute__((ext_vector_type(8))) unsigned short u16x8;
typedef __attribute__((ext_vector_type(4))) unsigned short u16x4;
typedef __attribute__((ext_vector_type(4))) float f32x4;
typedef __attribute__((ext_vector_type(2))) float f32x2;
typedef __attribute__((ext_vector_type(2))) unsigned int u32x2;
typedef __attribute__((address_space(3))) u16x8 lds_u16x8;
typedef __attribute__((address_space(3))) f32x4 lds_f32x4;
typedef __attribute__((address_space(3))) u32x2 lds_u32x2;
typedef __attribute__((address_space(3))) bf16x8 lds_bf16x8;

__device__ __forceinline__ float sigmoidf_(float v) { return 1.f / (1.f + __expf(-v)); }

__device__ __forceinline__ unsigned short f2bf(float f) {
  unsigned int u = __float_as_uint(f);
  u += 0x7fff + ((u >> 16) & 1);  // RNE
  return (unsigned short)(u >> 16);
}

__device__ __forceinline__ float bf2f(unsigned short u) {
  return __uint_as_float((unsigned int)u << 16);
}

// pk-fma: float2 fused multiply-add -> v_pk_fma_f32 on gfx950
__device__ __forceinline__ f32x2 pkfma_(f32x2 a, f32x2 b, f32x2 c) {
#if __has_builtin(__builtin_elementwise_fma)
  return __builtin_elementwise_fma(a, b, c);
#else
  return (f32x2){fmaf(a.x, b.x, c.x), fmaf(a.y, b.y, c.y)};
#endif
}

// async global->LDS, 16B per lane; LDS dest is wave-uniform base (+ lane*16 by HW)
__device__ __forceinline__ void gload16(const void* g, void* l) {
  __builtin_amdgcn_global_load_lds((const __attribute__((address_space(1))) unsigned int*)(g),
                                   (__attribute__((address_space(3))) unsigned int*)(l), 16, 0, 0);
}

// ---------------------------------------------------------------- dispatch A: transpose + prep
// blocks [0,2048): x fp32 NCHW -> xT bf16 NHWC + fused GAP partials (BW-bound).
// blocks [2048,4545): weight prep (latency-bound; overlaps transpose on the CU).
__global__ __launch_bounds__(256) void prep_transpose_kernel(
    const float* __restrict__ x, unsigned short* __restrict__ xT, float* __restrict__ partial,
    const float* __restrict__ w, unsigned short* __restrict__ wT,
    const float* __restrict__ w1, const float* __restrict__ b1, const float* __restrict__ bng,
    const float* __restrict__ bnb, const float* __restrict__ bnm, const float* __restrict__ bnv,
    const float* __restrict__ w2, const float* __restrict__ b2,
    unsigned short* __restrict__ w1b, unsigned short* __restrict__ w2b,
    float* __restrict__ b1f, float* __restrict__ b2p, float* __restrict__ zb) {
  __shared__ unsigned int tr[64 * 130];  // transpose: [px][128 ch-pair words + 2 pad]
  int ablk = blockIdx.x;
  if (ablk < 2048) {
    int tile = ablk & 255, b = ablk >> 8;
    int px0 = tile * 64;
    for (int i = threadIdx.x; i < 1024; i += 256) {
      int ch2 = i >> 3, pc = i & 7;
      const float* p0 = x + (((size_t)b * 256 + ch2 * 2) << 14) + px0 + pc * 8;
      const float4* a4 = (const float4*)p0;
      const float4* b4 = (const float4*)(p0 + 16384);
      float4 a0 = a4[0], a1 = a4[1], b0 = b4[0], b1v = b4[1];
      float fa[8] = {a0.x, a0.y, a0.z, a0.w, a1.x, a1.y, a1.z, a1.w};
      float fb[8] = {b0.x, b0.y, b0.z, b0.w, b1v.x, b1v.y, b1v.z, b1v.w};
      float sa = 0.f, sb = 0.f;
#pragma unroll
      for (int j = 0; j < 8; ++j) {
        sa += fa[j];
        sb += fb[j];
        unsigned int wv = (unsigned int)f2bf(fa[j]) | ((unsigned int)f2bf(fb[j]) << 16);
        tr[(pc * 8 + j) * 130 + ch2] = wv;
      }
      sa += __shfl_down(sa, 4, 8); sa += __shfl_down(sa, 2, 8); sa += __shfl_down(sa, 1, 8);
      sb += __shfl_down(sb, 4, 8); sb += __shfl_down(sb, 2, 8); sb += __shfl_down(sb, 1, 8);
      if ((threadIdx.x & 7) == 0) {
        atomicAdd(&partial[(b << 8) + ch2 * 2], sa);
        atomicAdd(&partial[(b << 8) + ch2 * 2 + 1], sb);
      }
    }
    __syncthreads();
    for (int i = threadIdx.x; i < 2048; i += 256) {
      int px = i >> 5, kc = i & 31;
      uint4 v = *(uint4*)&tr[px * 130 + kc * 4];
      *(uint4*)(xT + ((((size_t)b << 14)) + px0 + px) * 256 + kc * 8) = v;
    }
    return;
  }
  int blk = ablk - 2048;  // prep: 2497 blocks
  if (blk < 2304) {
    int n = blk * 256 + threadIdx.x;  // 589824
    int c = n & 31, oc = (n >> 5) & 255, t9 = n >> 13;
    int cb = t9 / 9, tap = t9 - cb * 9;
    wT[n] = f2bf(w[(oc * 256 + cb * 32 + c) * 9 + tap]);
  } else if (blk < 2464) {
    int n = (blk - 2304) * 256 + threadIdx.x;  // [0, 40960)
    int j = n & 7, r1 = n >> 3;
    int lane = r1 & 63, r2 = r1 >> 6;  // r2 in [0,80)
    int step = r2 % 5, gp = r2 / 5;
    int oc_l = lane & 15, kg2 = lane >> 4;
    int k = step * 32 + kg2 * 8 + j;
    int tap = k >> 4, icp = k & 15;
    int c = gp * 16 + oc_l;
    bool valid = (tap < 9) && ((icp >> 3) == (oc_l >> 3));
    float s = bng[c] * rsqrtf(bnv[c] + EPS_);
    w1b[n] = f2bf(valid ? w1[c * 72 + (icp & 7) * 9 + tap] * s : 0.f);
  } else if (blk < 2496) {
    int n = (blk - 2464) * 256 + threadIdx.x;  // [0, 8192)
    int j = n & 7, r1 = n >> 3;
    int lane = r1 & 63, r2 = r1 >> 6;  // [0,16)
    int ntile = r2 & 1, rnd = r2 >> 1;
    int nn = ntile * 16 + (lane & 15);
    int c = rnd * 32 + (lane >> 4) * 8 + j;
    w2b[n] = f2bf((nn < 25) ? w2[nn * 256 + c] : 0.f);
  } else {
    int n = threadIdx.x;
    if (n < 16) zb[n] = 0.f;
    if (n < 32) b2p[n] = (n < 25) ? b2[n] : -1e30f;
    if (n < 256) {
      float s = bng[n] * rsqrtf(bnv[n] + EPS_);
      b1f[n] = (b1[n] - bnm[n]) * s + bnb[n];
    }
  }
}

// ---------------------------------------------------------------- kernelgen via MFMA (R14)
__device__ __forceinline__ void kernelgen_body(
    int kblk, const unsigned short* __restrict__ xT, const unsigned short* __restrict__ w1b,
    const unsigned short* __restrict__ w2b, const float* __restrict__ b1f,
    const float* __restrict__ b2p, const unsigned short* __restrict__ zbuf,
    float* __restrict__ kern, char* smemc) {
  char* hbufc = smemc + 10368;
  int t = kblk & 63, b = kblk >> 6;
  int px0 = (t & 7) * 16, py0 = (t >> 3) * 16;
  int lane = threadIdx.x & 63, wid = threadIdx.x >> 6;
  int nx = lane & 15, kgrp = lane >> 4;
  const char* zc = (const char*)zbuf;

  size_t soff[3];
  bool okk[3];
#pragma unroll
  for (int i = 0; i < 3; ++i) {
    int g = wid * 162 + i * 64 + lane;
    int p = g >> 1, half = g & 1;
    int hy = p / 18, hx = p - hy * 18;
    int gy = py0 + hy - 1, gx = px0 + hx - 1;
    okk[i] = ((unsigned)gy < 128u) && ((unsigned)gx < 128u);
    soff[i] = (size_t)((gy & 127) * 128 + (gx & 127)) * 512 + half * 16;
  }
  const char* imgbase = (const char*)xT + (((size_t)b << 14) * 512);
  int dstb = wid * 2592;

  int aoff[5];
  int base_t = nx * 32 + (kgrp & 1) * 16;
#pragma unroll
  for (int s = 0; s < 5; ++s) {
    int tap = 2 * s + (kgrp >> 1);
    if (tap > 8) tap = 8;
    int dy = tap / 3, dx = tap - dy * 3;
    aoff[s] = dy * 576 + dx * 32 + base_t;
  }

  f32x4 acc2[4][2];
#pragma unroll
  for (int ml = 0; ml < 4; ++ml)
#pragma unroll
    for (int nt = 0; nt < 2; ++nt) acc2[ml][nt] = (f32x4)0.f;

#pragma unroll 1
  for (int gp = 0; gp < 16; ++gp) {
    __syncthreads();  // halo reads of prev round complete
    gload16(okk[0] ? imgbase + soff[0] + gp * 32 : zc, smemc + dstb);
    gload16(okk[1] ? imgbase + soff[1] + gp * 32 : zc, smemc + dstb + 1024);
    if (lane < 34) gload16(okk[2] ? imgbase + soff[2] + gp * 32 : zc, smemc + dstb + 2048);
    asm volatile("s_waitcnt vmcnt(0)" ::: "memory");
    __builtin_amdgcn_s_barrier();
    asm volatile("" ::: "memory");

    bf16x8 wf[5];
    const unsigned short* wp = w1b + ((size_t)(gp * 5) * 64 + lane) * 8;
#pragma unroll
    for (int s = 0; s < 5; ++s) wf[s] = *(const bf16x8*)(wp + s * 512);
    f32x4 bias = *(const f32x4*)(b1f + gp * 16 + kgrp * 4);

#pragma unroll
    for (int ml = 0; ml < 4; ++ml) {
      int m = wid * 4 + ml;
      f32x4 cf = (f32x4)0.f;
#pragma unroll
      for (int s = 0; s < 5; ++s) {
        bf16x8 xf = *(lds_bf16x8*)(smemc + m * 576 + aoff[s]);
        cf = __builtin_amdgcn_mfma_f32_16x16x32_bf16(wf[s], xf, cf, 0, 0, 0);
      }
      unsigned short us[4];
#pragma unroll
      for (int r = 0; r < 4; ++r) {
        float hv = cf[r] + bias[r];
        us[r] = f2bf(hv * sigmoidf_(hv));
      }
      unsigned int lo = (unsigned int)us[0] | ((unsigned int)us[1] << 16);
      unsigned int hi = (unsigned int)us[2] | ((unsigned int)us[3] << 16);
      *(lds_u32x2*)(hbufc + (m * 16 + nx) * 80 + (gp & 1) * 32 + kgrp * 8) = (u32x2){lo, hi};
    }

    if (gp & 1) {  // 32-ch window complete -> 1x1 MFMA chunk
      int rnd = gp >> 1;
      const unsigned short* w2p = w2b + ((size_t)(rnd * 2) * 64 + lane) * 8;
      bf16x8 w2f0 = *(const bf16x8*)(w2p);
      bf16x8 w2f1 = *(const bf16x8*)(w2p + 512);
#pragma unroll
      for (int ml = 0; ml < 4; ++ml) {
        int m = wid * 4 + ml;
        bf16x8 hf = *(lds_bf16x8*)(hbufc + (m * 16 + nx) * 80 + kgrp * 16);
        acc2[ml][0] = __builtin_amdgcn_mfma_f32_16x16x32_bf16(w2f0, hf, acc2[ml][0], 0, 0, 0);
        acc2[ml][1] = __builtin_amdgcn_mfma_f32_16x16x32_bf16(w2f1, hf, acc2[ml][1], 0, 0, 0);
      }
    }
  }

  f32x4 blo = *(const f32x4*)(b2p + kgrp * 4);
  f32x4 bhi = *(const f32x4*)(b2p + 16 + kgrp * 4);
#pragma unroll
  for (int ml = 0; ml < 4; ++ml) {
    int m = wid * 4 + ml;
    float v[8];
#pragma unroll
    for (int r = 0; r < 4; ++r) {
      v[r] = acc2[ml][0][r] + blo[r];
      v[4 + r] = acc2[ml][1][r] + bhi[r];
    }
    float mx = v[0];
#pragma unroll
    for (int i = 1; i < 8; ++i) mx = fmaxf(mx, v[i]);
    mx = fmaxf(mx, __shfl_xor(mx, 16, 64));
    mx = fmaxf(mx, __shfl_xor(mx, 32, 64));
    float sum = 0.f;
#pragma unroll
    for (int i = 0; i < 8; ++i) { v[i] = __expf(v[i] - mx); sum += v[i]; }
    sum += __shfl_xor(sum, 16, 64);
    sum += __shfl_xor(sum, 32, 64);
    float inv = 1.f / sum;
    size_t base = (((size_t)b * 25) << 14) + (size_t)(py0 + m) * 128 + px0 + nx;
#pragma unroll
    for (int nt = 0; nt < 2; ++nt)
#pragma unroll
      for (int r = 0; r < 4; ++r) {
        int n = nt * 16 + kgrp * 4 + r;
        if (n < 25) kern[base + ((size_t)n << 14)] = v[nt * 4 + r] * inv;
      }
  }
}

// conv body (R10 config) + statb epilogue (bf16 static when statb != null).
__device__ __forceinline__ void conv_body(int cblk, const unsigned short* __restrict__ xT,
                                          const unsigned short* __restrict__ wT,
                                          const float* __restrict__ bb,
                                          const float* __restrict__ bng,
                                          const float* __restrict__ bnb,
                                          const float* __restrict__ bnm,
                                          const float* __restrict__ bnv,
                                          const unsigned short* __restrict__ zbuf,
                                          unsigned short* __restrict__ statb,
                                          float* __restrict__ out, char* smemc) {
  int nb = ((cblk & 7) << 8) | (cblk >> 3);  // XCD swizzle (2048 % 8 == 0)
  int ocb = nb & 1, y = (nb >> 1) & 127, b = nb >> 8;
  int lane = threadIdx.x & 63, wid = threadIdx.x >> 6;
  int m_l = lane & 15, kgrp = lane >> 4;

  unsigned short* xs = (unsigned short*)smemc;  // ring: 4 x 8320B row slots
  const char* zc = (const char*)zbuf;

  int g0 = wid * 130 + lane, g1 = g0 + 64, g2 = wid * 130 + 128 + lane;  // g2: lane<2
  int px0_ = g0 >> 2, k0_ = g0 & 3, s0_ = k0_ ^ ((px0_ >> 1) & 3), gx0 = px0_ - 1;
  int px1_ = g1 >> 2, k1_ = g1 & 3, s1_ = k1_ ^ ((px1_ >> 1) & 3), gx1 = px1_ - 1;
  int px2_ = g2 >> 2, k2_ = g2 & 3, s2_ = k2_ ^ ((px2_ >> 1) & 3), gx2 = px2_ - 1;
  bool ok0 = (unsigned)gx0 < 128u, ok1 = (unsigned)gx1 < 128u, ok2 = (unsigned)gx2 < 128u;
  int off0 = gx0 * 512 + s0_ * 16, off1 = gx1 * 512 + s1_ * 16, off2 = gx2 * 512 + s2_ * 16;
  int d0 = (wid * 130) * 16, d1 = d0 + 1024, d2 = d0 + 2048;

#define STAGE_ROW(slotB_, cbn_, khn_)                                                       \
  do {                                                                                      \
    int gy_ = y + (khn_)-1;                                                                 \
    bool gyok_ = ((unsigned)gy_ < 128u);                                                    \
    const char* rb_ =                                                                       \
        (const char*)xT + (((size_t)b << 14) + (size_t)(gy_ & 127) * 128) * 512 + (cbn_)*64;\
    gload16((gyok_ && ok0) ? rb_ + off0 : zc, smemc + (slotB_) + d0);                       \
    gload16((gyok_ && ok1) ? rb_ + off1 : zc, smemc + (slotB_) + d1);                       \
    if (lane < 2) gload16((gyok_ && ok2) ? rb_ + off2 : zc, smemc + (slotB_) + d2);         \
  } while (0)

  f32x4 acc[8][2];
#pragma unroll
  for (int mt = 0; mt < 8; ++mt)
#pragma unroll
    for (int nt = 0; nt < 2; ++nt) acc[mt][nt] = (f32x4)0.f;

  STAGE_ROW(0, 0, 0);
  STAGE_ROW(8320, 0, 1);
  STAGE_ROW(16640, 0, 2);
  STAGE_ROW(24960, 1, 0);

  int oc0 = ocb * 128 + wid * 32;
  const unsigned short* wTb = wT + ((size_t)(oc0 + m_l) * 32 + kgrp * 8);
  int khn = 1, cbn = 1;

#pragma unroll 1
  for (int P = 0; P < 12; ++P) {
    if (P < 11) {
      asm volatile("s_waitcnt vmcnt(6)" ::: "memory");
    } else {
      asm volatile("s_waitcnt vmcnt(0)" ::: "memory");
    }
    __builtin_amdgcn_s_barrier();
    asm volatile("" ::: "memory");
#pragma unroll
    for (int half = 0; half < 2; ++half) {
      int R = 2 * P + half;
      const unsigned short* xb = xs + (R & 3) * 4160;
#pragma unroll
      for (int kw = 0; kw < 3; ++kw) {
        bf16x8 bfrag[2];
        const unsigned short* wb = wTb + (size_t)(R * 3 + kw) * 8192;
#pragma unroll
        for (int nt = 0; nt < 2; ++nt) bfrag[nt] = *(const bf16x8*)(wb + nt * 512);
#pragma unroll
        for (int mt = 0; mt < 8; ++mt) {
          int apx = mt * 16 + m_l + kw;
          int kk = kgrp ^ ((apx >> 1) & 3);
          bf16x8 af =
              *(__attribute__((address_space(3))) bf16x8*)(&xb[apx * 32 + kk * 8]);
#pragma unroll
          for (int nt = 0; nt < 2; ++nt)
            acc[mt][nt] =
                __builtin_amdgcn_mfma_f32_16x16x32_bf16(af, bfrag[nt], acc[mt][nt], 0, 0, 0);
        }
      }
    }
    __builtin_amdgcn_s_barrier();
    asm volatile("" ::: "memory");
    if (P < 10) {
      STAGE_ROW((size_t)((2 * P + 4) & 3) * 8320, cbn, khn);
      ++khn;
      if (khn == 3) { khn = 0; ++cbn; }
      STAGE_ROW((size_t)((2 * P + 5) & 3) * 8320, cbn, khn);
      ++khn;
      if (khn == 3) { khn = 0; ++cbn; }
    }
  }
#undef STAGE_ROW

  float scale2[2], bias2[2];
#pragma unroll
  for (int nt = 0; nt < 2; ++nt) {
    int oc = oc0 + nt * 16 + m_l;
    float s = bng[oc] * rsqrtf(bnv[oc] + EPS_);
    scale2[nt] = s;
    bias2[nt] = bnb[oc] + (bb[oc] - bnm[oc]) * s;
  }
  if (statb) {
#pragma unroll
    for (int nt = 0; nt < 2; ++nt) {
      size_t obase = (((size_t)(b * 256 + oc0 + nt * 16 + m_l)) << 14) + y * 128 + kgrp * 4;
#pragma unroll
      for (int mt = 0; mt < 8; ++mt) {
        f32x4 v = acc[mt][nt];
        u16x4 o;
#pragma unroll
        for (int r = 0; r < 4; ++r) {
          float hv = v[r] * scale2[nt] + bias2[nt];
          o[r] = f2bf(hv * sigmoidf_(hv));
        }
        *(u16x4*)(statb + obase + mt * 16) = o;
      }
    }
  } else {
#pragma unroll
    for (int nt = 0; nt < 2; ++nt) {
      size_t obase = (((size_t)(b * 256 + oc0 + nt * 16 + m_l)) << 14) + y * 128 + kgrp * 4;
#pragma unroll
      for (int mt = 0; mt < 8; ++mt) {
        f32x4 v = acc[mt][nt];
        float o4[4];
#pragma unroll
        for (int r = 0; r < 4; ++r) {
          float hv = v[r] * scale2[nt] + bias2[nt];
          o4[r] = hv * sigmoidf_(hv);
        }
        *(f32x4*)(out + obase + mt * 16) = (f32x4){o4[0], o4[1], o4[2], o4[3]};
      }
    }
  }
}

// gate body: one block per batch image (8 blocks at the tail of dispatch B)
__device__ __forceinline__ void gate_body(int b, const float* __restrict__ partial,
                                          const float* __restrict__ gw,
                                          const float* __restrict__ gb,
                                          float* __restrict__ gout, char* smemc) {
  float* red = (float*)smemc;
  int t = threadIdx.x;
  float s = partial[b * 256 + t] * gw[t];
#pragma unroll
  for (int off = 32; off; off >>= 1) s += __shfl_down(s, off, 64);
  if ((t & 63) == 0) red[t >> 6] = s;
  __syncthreads();
  if (t == 0) {
    float tot = (red[0] + red[1]) + (red[2] + red[3]);
    gout[b] = sigmoidf_(tot * (1.f / 16384.f) + gb[0]);
  }
}

// ---------------------------------------------------------------- dispatch B
// [0,kgN): MFMA kernelgen; [kgN,kgN+2048): conv; tail 8 blocks: gate.
__global__ __launch_bounds__(256, 4) void fused_kernel(
    int kgN, const unsigned short* __restrict__ xT, const unsigned short* __restrict__ wT,
    const unsigned short* __restrict__ w1b, const unsigned short* __restrict__ w2b,
    const float* __restrict__ b1f, const float* __restrict__ b2p, float* __restrict__ kern,
    const float* __restrict__ bb, const float* __restrict__ bng, const float* __restrict__ bnb,
    const float* __restrict__ bnm, const float* __restrict__ bnv,
    const unsigned short* __restrict__ zbuf, unsigned short* __restrict__ statb,
    float* __restrict__ out, const float* __restrict__ partial, const float* __restrict__ gw,
    const float* __restrict__ gb, float* __restrict__ gout) {
  __shared__ char smem[33280];  // conv ring 33,280B; kg uses 30,848B
  int blk = (int)blockIdx.x;
  if (blk < kgN) {
    kernelgen_body(blk, xT, w1b, w2b, b1f, b2p, zbuf, kern, smem);
  } else if (blk < kgN + 2048) {
    conv_body(blk - kgN, xT, wT, bb, bng, bnb, bnm, bnv, zbuf, statb, out, smem);
  } else {
    gate_body(blk - kgN - 2048, partial, gw, gb, gout, smem);
  }
}

// ---------------------------------------------------------------- CARAFE + blend (dispatch C)
// 32-wide tiles (16ch x 16y x 32x, patch [20 rows][36 px][16 ch]).
// GRANULE XOR-SWIZZLE (rule #21, both sides): involution G <-> G ^ ((G>>3)&7) on the
// absolute 16B-granule index. Staging keeps the LINEAR DMA dest and pre-swizzles the
// per-lane SOURCE (logical = involution(physical)); reads apply the same involution:
// addr(p) = (p<<5) ^ (((p>>2)&7)<<4), half-1 at ^16. Breaks the 8-way bank conflict
// of the 32B-stride [px][16ch] layout (lanes l,l+4,... formerly same bank).
__global__ __launch_bounds__(256) void carafe_blend_kernel(
    const unsigned short* __restrict__ xT, const float* __restrict__ kern,
    const float* __restrict__ gq, const unsigned short* __restrict__ statb,
    float* __restrict__ out) {
  int blk = blockIdx.x;  // 4096
  int xcd = blk & 7, r = blk >> 3;
  int ocg = r & 15;
  int tile = (r >> 4) * 8 + xcd;  // 0..255
  int b = tile >> 5, rem = tile & 31;
  int by = rem >> 2, bx = rem & 3;  // by 0..7 (16 rows), bx 0..3 (32 px)
  __shared__ unsigned short xc[720 * 16];  // [20 rows x 36 px][16 ch], granule-swizzled
  int lane = threadIdx.x & 63, wid = threadIdx.x >> 6;
  int lx = threadIdx.x & 31, ty = threadIdx.x >> 5;  // ty 0..7
  float gv = gq[b];
  int y0 = ty * 2;
  int gy0 = by * 16 + y0, gx = bx * 32 + lx;

  // kern prefetch (issued before staging DMA)
  float kv0[25], kv1[25];
  size_t kb = (((size_t)b * 25) << 14) + (size_t)gy0 * 128 + gx;
#pragma unroll
  for (int n = 0; n < 25; ++n) {
    kv0[n] = kern[kb + ((size_t)n << 14)];
    kv1[n] = kern[kb + ((size_t)n << 14) + 128];
  }

  // halo staging: 1440 granules of 16B; wave w covers physical granules [w*360, +360).
  // Source computed for LOGICAL granule = involution(physical).
  int dstb = wid * 5760;
#pragma unroll
  for (int i = 0; i < 6; ++i) {
    int gp = wid * 360 + i * 64 + lane;  // physical granule (DMA dest = gp*16)
    if (i < 5 || lane < 40) {
      int gl = gp ^ ((gp >> 3) & 7);  // logical granule
      int p = gl >> 1, half = gl & 1;
      int py = p / 36, pxx = p - py * 36;
      int yy = by * 16 + py - 2, xx = bx * 32 + pxx - 2;
      yy = yy < 0 ? -yy : (yy > 127 ? 254 - yy : yy);
      xx = xx < 0 ? -xx : (xx > 127 ? 254 - xx : xx);
      gload16((const char*)xT + ((size_t)((b << 14) + yy * 128 + xx) * 512) + ocg * 32 +
                  half * 16,
              (char*)xc + dstb + i * 1024);
    }
  }
  asm volatile("s_waitcnt vmcnt(0)" ::: "memory");
  __syncthreads();

  f32x2 car0[8], car1[8];
#pragma unroll
  for (int c = 0; c < 8; ++c) { car0[c] = (f32x2)0.f; car1[c] = (f32x2)0.f; }
#pragma unroll
  for (int n = 0; n < 25; ++n) {
    int ki = n / 5, kj = n - ki * 5;
    int p0 = (y0 + ki) * 36 + lx + kj;
    int A0 = (p0 << 5) ^ (((p0 >> 2) & 7) << 4);          // swizzled byte addr, row 0
    int B0 = ((p0 + 36) << 5) ^ ((((p0 + 36) >> 2) & 7) << 4);  // row +1
    f32x2 kvv0 = (f32x2){kv0[n], kv0[n]}, kvv1 = (f32x2){kv1[n], kv1[n]};
    union { u16x8 s8; unsigned int u[4]; } a0, a1, b0, b1;
    a0.s8 = *(lds_u16x8*)((char*)xc + A0);
    a1.s8 = *(lds_u16x8*)((char*)xc + (A0 ^ 16));
    b0.s8 = *(lds_u16x8*)((char*)xc + B0);
    b1.s8 = *(lds_u16x8*)((char*)xc + (B0 ^ 16));
#pragma unroll
    for (int j = 0; j < 4; ++j) {
      f32x2 f0 = (f32x2){__uint_as_float(a0.u[j] << 16), __uint_as_float(a0.u[j] & 0xffff0000u)};
      f32x2 f1 = (f32x2){__uint_as_float(a1.u[j] << 16), __uint_as_float(a1.u[j] & 0xffff0000u)};
      f32x2 g0 = (f32x2){__uint_as_float(b0.u[j] << 16), __uint_as_float(b0.u[j] & 0xffff0000u)};
      f32x2 g1 = (f32x2){__uint_as_float(b1.u[j] << 16), __uint_as_float(b1.u[j] & 0xffff0000u)};
      car0[j] = pkfma_(f0, kvv0, car0[j]);
      car0[4 + j] = pkfma_(f1, kvv0, car0[4 + j]);
      car1[j] = pkfma_(g0, kvv1, car1[j]);
      car1[4 + j] = pkfma_(g1, kvv1, car1[4 + j]);
    }
  }
  if (statb) {
#pragma unroll
    for (int j = 0; j < 8; ++j) {
      size_t ob0 = (((size_t)(b * 256 + ocg * 16 + 2 * j)) << 14) + (size_t)gy0 * 128 + gx;
      size_t ob1 = ob0 + 16384;
      float s00 = bf2f(statb[ob0]), s01 = bf2f(statb[ob0 + 128]);
      float s10 = bf2f(statb[ob1]), s11 = bf2f(statb[ob1 + 128]);
      out[ob0] = fmaf(gv, car0[j].x - s00, s00);
      out[ob0 + 128] = fmaf(gv, car1[j].x - s01, s01);
      out[ob1] = fmaf(gv, car0[j].y - s10, s10);
      out[ob1 + 128] = fmaf(gv, car1[j].y - s11, s11);
    }
  } else {
#pragma unroll
    for (int j = 0; j < 8; ++j) {
      size_t ob0 = (((size_t)(b * 256 + ocg * 16 + 2 * j)) << 14) + (size_t)gy0 * 128 + gx;
      size_t ob1 = ob0 + 16384;
      float s00 = out[ob0], s01 = out[ob0 + 128];
      float s10 = out[ob1], s11 = out[ob1 + 128];
      out[ob0] = fmaf(gv, car0[j].x - s00, s00);
      out[ob0 + 128] = fmaf(gv, car1[j].x - s01, s01);
      out[ob1] = fmaf(gv, car0[j].y - s10, s10);
      out[ob1 + 128] = fmaf(gv, car1[j].y - s11, s11);
    }
  }
}

// ---------------------------------------------------------------- launcher
extern "C" void kernel_launch(void* const* d_in, const int* in_sizes, int n_in,
                              void* d_out, int out_size, void* d_ws, size_t ws_size,
                              hipStream_t stream) {
  const float* x      = (const float*)d_in[0];
  const float* ke_w1  = (const float*)d_in[1];
  const float* ke_b1  = (const float*)d_in[2];
  const float* ke_bng = (const float*)d_in[3];
  const float* ke_bnb = (const float*)d_in[4];
  const float* ke_bnm = (const float*)d_in[5];
  const float* ke_bnv = (const float*)d_in[6];
  const float* ke_w2  = (const float*)d_in[7];
  const float* ke_b2  = (const float*)d_in[8];
  const float* bs_w   = (const float*)d_in[9];
  const float* bs_b   = (const float*)d_in[10];
  const float* bs_bng = (const float*)d_in[11];
  const float* bs_bnb = (const float*)d_in[12];
  const float* bs_bnm = (const float*)d_in[13];
  const float* bs_bnv = (const float*)d_in[14];
  const float* g_w    = (const float*)d_in[15];
  const float* g_b    = (const float*)d_in[16];
  float* outp = (float*)d_out;

  char* ws = (char*)d_ws;
  float* kern        = (float*)(ws);                      // 13,107,200 B
  float* partial     = (float*)(ws + 13107200);           // 8,192 B
  float* gout        = (float*)(ws + 13115392);           // bytes 0-31 of 256B slot
  float* zbuff       = (float*)(ws + 13115392 + 128);     // 64B zero pad
  unsigned short* wT = (unsigned short*)(ws + 13115648);  // 1,179,648 B
  unsigned short* xT = (unsigned short*)(ws + 14295296);  // 67,108,864 B -> 81,404,160 total

  // kg MFMA tables (99,456 B in a 131,072 B slot) + optional bf16 static buffer
  // (67,108,864 B). statb enables write-only out in carafe (no RMW read).
  const size_t USED = 81404160;
  const size_t TBL = 131072;
  bool bigws = ws_size >= USED + TBL;
  bool bigws2 = ws_size >= USED + TBL + 67108864;
  unsigned short *w1b, *w2b;
  float *b1f, *b2p;
  if (bigws) {
    w1b = (unsigned short*)(ws + USED);
    w2b = (unsigned short*)(ws + USED + 81920);
    b1f = (float*)(ws + USED + 98304);
    b2p = (float*)(ws + USED + 99328);
  } else {
    w1b = (unsigned short*)((char*)d_out + 52428800);
    w2b = (unsigned short*)((char*)d_out + 52428800 + 81920);
    b1f = (float*)((char*)d_out + 52428800 + 98304);
    b2p = (float*)((char*)d_out + 52428800 + 99328);
  }
  unsigned short* statb = bigws2 ? (unsigned short*)(ws + USED + TBL) : nullptr;

  hipMemsetAsync(partial, 0, 2048 * sizeof(float), stream);  // GAP accumulators
  // dispatch A: transpose (2048) + prep (2497) overlapped
  prep_transpose_kernel<<<4545, 256, 0, stream>>>(x, xT, partial, bs_w, wT, ke_w1, ke_b1,
                                                  ke_bng, ke_bnb, ke_bnm, ke_bnv, ke_w2,
                                                  ke_b2, w1b, w2b, b1f, b2p, zbuff);
  if (bigws) {
    // dispatch B: kg 512 + conv 2048 + gate 8
    fused_kernel<<<2568, 256, 0, stream>>>(512, xT, wT, w1b, w2b, b1f, b2p, kern, bs_b,
                                           bs_bng, bs_bnb, bs_bnm, bs_bnv,
                                           (const unsigned short*)zbuff, statb, outp,
                                           partial, g_w, g_b, gout);
  } else {
    // serial fallback: tables live in d_out (dead until conv runs after kernelgen)
    fused_kernel<<<512, 256, 0, stream>>>(512, xT, wT, w1b, w2b, b1f, b2p, kern, bs_b,
                                          bs_bng, bs_bnb, bs_bnm, bs_bnv,
                                          (const unsigned short*)zbuff, statb, outp,
                                          partial, g_w, g_b, gout);
    fused_kernel<<<2056, 256, 0, stream>>>(0, xT, wT, w1b, w2b, b1f, b2p, kern, bs_b,
                                           bs_bng, bs_bnb, bs_bnm, bs_bnv,
                                           (const unsigned short*)zbuff, statb, outp,
                                           partial, g_w, g_b, gout);
  }
  carafe_blend_kernel<<<4096, 256, 0, stream>>>(xT, kern, gout, statb, outp);
}